// Round 1
// baseline (285.132 us; speedup 1.0000x reference)
//
#include <hip/hip_runtime.h>

// Problem constants (TokenEmbedding_55997783605696)
#define BATCH    32
#define SEQLEN   4096
#define CIN      7
#define NKERN    74
#define NCOL     512     // 7*73 + 1
#define TT       16      // timesteps per block tile
#define NTAP     24      // collapsed 1D filter length, delta in [-22, +1]
#define HALO     22
#define XROW     40      // xs row stride in floats = TT + NTAP (160 B, 16B-aligned)

// out[b,t, c*73+k] = sum_m W[k][m] * x[b, t+m-22, c]
// W[k][m] = kernels[k][7 - m/3][m%3]   (m = 3*(7-i) + j)
// Boundary: x==0 outside [0,L); additionally at t==L-1 all m%3==2 taps with
// m<23 drop (reference's time-axis pad zeroes win[:, L] for every i, even
// where x[t+m-22] itself is in-range). m==23's x is already 0 there.
//
// v2: LDS-staged epilogue. Compute mapping stays 1 column/thread (clean
// per-thread weights), but results are staged into a 16x512 LDS tile and
// stored as a purely contiguous 32 KB block copy with global_store_dwordx4
// (1 KB/wave-inst), instead of 64 scalar stores at 2048-B stride.
__global__ __launch_bounds__(256) void dilated_convbank_kernel(
    const float* __restrict__ x,     // (B, L, C)   fp32
    const float* __restrict__ kern,  // (74, 8, 3)  fp32
    float* __restrict__ out)         // (B, L, 512) fp32
{
    __shared__ __align__(16) float xs[CIN * XROW];   // 1.12 KB
    __shared__ __align__(16) float Ot[TT * NCOL];    // 32 KB

    const int tid = threadIdx.x;
    const int t0  = blockIdx.x * TT;     // 256 tiles
    const int b   = blockIdx.y;          // 32 batches

    // Phase 1: x tile, transposed to [c][t_local], zero-padded halo
    for (int idx = tid; idx < CIN * XROW; idx += 256) {
        const int c = idx / XROW, tl = idx - c * XROW;
        const int t = t0 - HALO + tl;
        float v = 0.f;
        if (t >= 0 && t < SEQLEN)
            v = x[(b * SEQLEN + t) * CIN + c];
        xs[c * XROW + tl] = v;
    }
    __syncthreads();

    const bool lastTile = (t0 + TT == SEQLEN);

    // unroll 1: keep only one column's {W[24], xw[40], acc[16]} live at a
    // time -> ~110 VGPR -> 4 waves/SIMD alongside the 33 KB LDS (4 blocks/CU).
    #pragma unroll 1
    for (int cc = 0; cc < 2; ++cc) {
        const int q = tid + cc * 256;    // output column 0..511
        int c, k;
        if (q == NCOL - 1) { c = 0; k = NKERN - 1; }
        else               { c = q / 73; k = q - c * 73; }

        // Permuted filter taps straight from global (7.1 KB table, L1-hot).
        float W[NTAP];
        #pragma unroll
        for (int m = 0; m < NTAP; ++m) {
            const int i = 7 - m / 3, j = m % 3;
            W[m] = kern[(k * 8 + i) * 3 + j];
        }

        // window xs[c][0..39] via aligned float4 LDS reads (broadcast: ~73
        // lanes share a channel -> conflict-free)
        const float* xrow = &xs[c * XROW];
        float xw[XROW];
        #pragma unroll
        for (int v = 0; v < XROW / 4; ++v) {
            const float4 f = ((const float4*)xrow)[v];
            xw[4 * v + 0] = f.x; xw[4 * v + 1] = f.y;
            xw[4 * v + 2] = f.z; xw[4 * v + 3] = f.w;
        }

        float acc[TT];
        #pragma unroll
        for (int tt = 0; tt < TT; ++tt) acc[tt] = 0.f;
        #pragma unroll
        for (int m = 0; m < NTAP; ++m) {
            const float w = W[m];
            #pragma unroll
            for (int tt = 0; tt < TT; ++tt)
                acc[tt] += w * xw[tt + m];
        }
        // t == L-1: drop the j==2 taps whose x is in-range
        if (lastTile) {
            #pragma unroll
            for (int m = 2; m < 23; m += 3)
                acc[TT - 1] -= W[m] * xw[TT - 1 + m];
        }

        // Stage to LDS tile [t][q]: lanes have consecutive q -> consecutive
        // banks, conflict-free ds_write_b32.
        #pragma unroll
        for (int tt = 0; tt < TT; ++tt)
            Ot[tt * NCOL + q] = acc[tt];
    }
    __syncthreads();

    // Epilogue: contiguous 32 KB block copy, dwordx4, fully coalesced.
    const float4* s4 = (const float4*)Ot;
    float4* o4 = (float4*)(out + ((size_t)b * SEQLEN + t0) * NCOL);
    #pragma unroll
    for (int i = 0; i < (TT * NCOL) / 4 / 256; ++i)   // 8 iters
        o4[tid + i * 256] = s4[tid + i * 256];
}

extern "C" void kernel_launch(void* const* d_in, const int* in_sizes, int n_in,
                              void* d_out, int out_size, void* d_ws, size_t ws_size,
                              hipStream_t stream) {
    const float* x    = (const float*)d_in[0]; // (32,4096,7)  fp32
    const float* kern = (const float*)d_in[1]; // (74,8,3)     fp32
    float* out = (float*)d_out;                // (32,4096,512) fp32

    dim3 grid(SEQLEN / TT, BATCH);
    dilated_convbank_kernel<<<grid, 256, 0, stream>>>(x, kern, out);
}

// Round 2
// 268.630 us; speedup vs baseline: 1.0614x; 1.0614x over previous
//
#include <hip/hip_runtime.h>

// Problem constants (TokenEmbedding_55997783605696)
#define BATCH    32
#define SEQLEN   4096
#define CIN      7
#define NKERN    74
#define NCOL     512     // 7*73 + 1
#define TT       64      // timesteps per block tile
#define TG       16      // t-group (register blocking)
#define NTAP     24      // collapsed 1D filter length, delta in [-22, +1]
#define HALO     22
#define WROW     25      // W row stride in floats (odd -> broadcast-friendly)
#define XROW     88      // xs row stride in floats = TT + 24 (16B-aligned rows)

// out[b,t, c*73+k] = sum_m W[k][m] * x[b, t+m-22, c]
// W[k][m] = kernels[k][7 - m/3][m%3]   (m = 3*(7-i) + j)
// Boundary: x==0 outside [0,L); additionally at t==L-1 all m%3==2 taps with
// m<23 drop (reference's time-axis pad zeroes win[:, L] for every i, even
// where x[t+m-22] itself is in-range). m==23's x is already 0 there.
//
// v3: latency/occupancy attack. v2 proved stores are not the bottleneck
// (fill-identical store pattern regressed). v1's issue efficiency was ~25%
// -> latency-bound. Changes vs v1:
//   * TT 32->64: halves per-block staging/barrier overhead per output.
//   * unroll 1 on cc AND g: one column-group live at a time (~95 VGPR)
//     -> 4-5 waves/SIMD instead of ~3 with v1's fully-unrolled cc.
//   * keep v1's direct scalar stores (proven better than LDS-staged copy).
__global__ __launch_bounds__(256) void dilated_convbank_kernel(
    const float* __restrict__ x,     // (B, L, C)   fp32
    const float* __restrict__ kern,  // (74, 8, 3)  fp32
    float* __restrict__ out)         // (B, L, 512) fp32
{
    __shared__ __align__(16) float Ws[NKERN * WROW]; // 7.4 KB
    __shared__ __align__(16) float xs[CIN * XROW];   // 2.5 KB

    const int tid = threadIdx.x;
    const int t0  = blockIdx.x * TT;     // 64 tiles
    const int b   = blockIdx.y;          // 32 batches

    // Phase 0: permuted filter load
    for (int idx = tid; idx < NKERN * NTAP; idx += 256) {
        const int k = idx / NTAP, m = idx - k * NTAP;
        const int i = 7 - m / 3, j = m % 3;
        Ws[k * WROW + m] = kern[(k * 8 + i) * 3 + j];
    }
    // Phase 1: x tile, transposed to [c][t_local], zero-padded halo
    for (int idx = tid; idx < CIN * XROW; idx += 256) {
        const int c = idx / XROW, tl = idx - c * XROW;
        const int t = t0 - HALO + tl;
        float v = 0.f;
        if (t >= 0 && t < SEQLEN)
            v = x[(b * SEQLEN + t) * CIN + c];
        xs[c * XROW + tl] = v;
    }
    __syncthreads();

    const bool lastTile = (t0 + TT == SEQLEN);

    // unroll 1 on cc: only one column's {W[24]} + one g-group's {xw[40],
    // acc[16]} live at a time -> low VGPR -> more waves/SIMD.
    #pragma unroll 1
    for (int cc = 0; cc < 2; ++cc) {
        const int q = tid + cc * 256;    // output column 0..511
        int c, k;
        if (q == NCOL - 1) { c = 0; k = NKERN - 1; }
        else               { c = q / 73; k = q - c * 73; }

        float W[NTAP];
        #pragma unroll
        for (int m = 0; m < NTAP; ++m) W[m] = Ws[k * WROW + m];
        const float* xrow = &xs[c * XROW];

        // out base for this column: lanes have consecutive q -> coalesced
        float* ob = out + ((size_t)b * SEQLEN + t0) * NCOL + q;

        #pragma unroll 1
        for (int g = 0; g < TT / TG; ++g) {
            // window xs[c][g*TG .. g*TG+39] via aligned float4 LDS reads
            // (g*TG floats = 64 B -> 16B-aligned). ~73 lanes share a channel
            // -> broadcast, conflict-free.
            float xw[TG + NTAP];
            #pragma unroll
            for (int v = 0; v < (TG + NTAP) / 4; ++v) {
                const float4 f = ((const float4*)(xrow + g * TG))[v];
                xw[v * 4 + 0] = f.x; xw[v * 4 + 1] = f.y;
                xw[v * 4 + 2] = f.z; xw[v * 4 + 3] = f.w;
            }
            float acc[TG];
            #pragma unroll
            for (int tt = 0; tt < TG; ++tt) acc[tt] = 0.f;
            #pragma unroll
            for (int m = 0; m < NTAP; ++m) {
                const float w = W[m];
                #pragma unroll
                for (int tt = 0; tt < TG; ++tt)
                    acc[tt] += w * xw[tt + m];
            }
            // t == L-1: drop the j==2 taps whose x is in-range
            if (lastTile && g == TT / TG - 1) {
                #pragma unroll
                for (int m = 2; m < 23; m += 3)
                    acc[TG - 1] -= W[m] * xw[TG - 1 + m];
            }
            #pragma unroll
            for (int tt = 0; tt < TG; ++tt)
                ob[(size_t)(g * TG + tt) * NCOL] = acc[tt];
        }
    }
}

extern "C" void kernel_launch(void* const* d_in, const int* in_sizes, int n_in,
                              void* d_out, int out_size, void* d_ws, size_t ws_size,
                              hipStream_t stream) {
    const float* x    = (const float*)d_in[0]; // (32,4096,7)  fp32
    const float* kern = (const float*)d_in[1]; // (74,8,3)     fp32
    float* out = (float*)d_out;                // (32,4096,512) fp32

    dim3 grid(SEQLEN / TT, BATCH);
    dilated_convbank_kernel<<<grid, 256, 0, stream>>>(x, kern, out);
}